// Round 4
// baseline (367.749 us; speedup 1.0000x reference)
//
#include <hip/hip_runtime.h>

typedef __attribute__((ext_vector_type(8))) __bf16 bf16x8;
typedef __attribute__((ext_vector_type(4))) float f32x4;

constexpr int T  = 4096;   // tokens
constexpr int Dm = 1024;   // model dim
constexpr int Hm = 4096;   // hidden dim
constexpr int NE = 8;      // experts
constexpr int CAP = 1075;  // capacity  round(2*4096*1.05/8)
constexpr int CP  = 1152;  // capacity padded to 9*128

static __device__ __forceinline__ unsigned short f2bf(float f) {
  unsigned int u = __float_as_uint(f);
  u += 0x7FFFu + ((u >> 16) & 1u);   // RNE
  return (unsigned short)(u >> 16);
}

static __device__ __forceinline__ void gload_lds16(const void* g, void* l) {
  __builtin_amdgcn_global_load_lds(
      (const __attribute__((address_space(1))) void*)g,
      (__attribute__((address_space(3))) void*)l, 16, 0, 0);
}

// ---------------- device bodies ----------------

// transpose+convert one 64(k) x 32(n) tile: W [Kd][N] f32 -> Wt [N][Kd] bf16
static __device__ __forceinline__ void transpose_body(
    float (*tile)[33], const float* __restrict__ W, unsigned short* __restrict__ Wt,
    int Kd, int N, int e, int n0, int k0) {
  const float* src = W + ((long long)e * Kd + k0) * N + n0;
  const int tid = threadIdx.x;
  const int r = tid >> 3;            // 0..31
  const int c4 = (tid & 7) * 4;
#pragma unroll
  for (int hh = 0; hh < 2; ++hh) {
    float4 v = *(const float4*)(src + (long long)(r + 32 * hh) * N + c4);
    tile[r + 32 * hh][c4] = v.x; tile[r + 32 * hh][c4 + 1] = v.y;
    tile[r + 32 * hh][c4 + 2] = v.z; tile[r + 32 * hh][c4 + 3] = v.w;
  }
  __syncthreads();
  const int n = tid >> 4;            // 0..15
  const int k4 = (tid & 15) * 4;
  unsigned short* dst = Wt + ((long long)e * N + n0) * Kd + k0;
#pragma unroll
  for (int hh = 0; hh < 2; ++hh) {
    int nn = n + 16 * hh;
    ushort4 o;
    o.x = f2bf(tile[k4][nn]);     o.y = f2bf(tile[k4 + 1][nn]);
    o.z = f2bf(tile[k4 + 2][nn]); o.w = f2bf(tile[k4 + 3][nn]);
    *(ushort4*)(dst + (long long)nn * Kd + k4) = o;
  }
}

// router body for token group (4 tokens per block of 256 threads)
static __device__ __forceinline__ void router_body(
    const float* __restrict__ x, const float* __restrict__ Wg,
    int* __restrict__ topi, float* __restrict__ topw, int blk) {
  int t = blk * 4 + (threadIdx.x >> 6);
  int lane = threadIdx.x & 63;
  const float* xr = x + (size_t)t * Dm;
  float acc[NE];
#pragma unroll
  for (int e = 0; e < NE; ++e) acc[e] = 0.f;
  for (int i = lane * 4; i < Dm; i += 256) {
    float4 xv = *(const float4*)(xr + i);
#pragma unroll
    for (int e = 0; e < NE; ++e) {
      float4 wv = *(const float4*)(Wg + e * Dm + i);
      acc[e] += xv.x * wv.x + xv.y * wv.y + xv.z * wv.z + xv.w * wv.w;
    }
  }
#pragma unroll
  for (int off = 32; off > 0; off >>= 1) {
#pragma unroll
    for (int e = 0; e < NE; ++e) acc[e] += __shfl_xor(acc[e], off, 64);
  }
  if (lane == 0) {
    float mx = acc[0];
#pragma unroll
    for (int e = 1; e < NE; ++e) mx = fmaxf(mx, acc[e]);
    float g[NE];
    float s = 0.f;
#pragma unroll
    for (int e = 0; e < NE; ++e) { g[e] = expf(acc[e] - mx); s += g[e]; }
    int i0 = 0; float v0 = g[0];
#pragma unroll
    for (int e = 1; e < NE; ++e) if (g[e] > v0) { v0 = g[e]; i0 = e; }
    int i1 = -1; float v1 = -1e30f;
#pragma unroll
    for (int e = 0; e < NE; ++e) {
      if (e == i0) continue;
      if (g[e] > v1) { v1 = g[e]; i1 = e; }
    }
    float inv = 1.f / s;
    topi[t * 2] = i0; topi[t * 2 + 1] = i1;
    topw[t * 2] = v0 * inv; topw[t * 2 + 1] = v1 * inv;
  }
}

// GEMM tile body: C[mb*128..][nb*128..] = A @ Bt^T + bias, m97-swizzled staging.
template <bool GELU, bool OUT_BF16>
static __device__ __forceinline__ void gemm_body(
    unsigned short* Alds, unsigned short* Blds,
    const unsigned short* __restrict__ A, const unsigned short* __restrict__ Bt,
    const float* __restrict__ bias, void* __restrict__ Out,
    int Kd, int N, int mb, int nb) {
  const unsigned short* Ab  = A  + (long long)mb * 128 * Kd;
  const unsigned short* Btb = Bt + (long long)nb * 128 * Kd;

  const int tid = threadIdx.x;
  const int lane = tid & 63;
  const int wid = tid >> 6;
  const int wr = (wid >> 1) * 64;
  const int wc = (wid & 1) * 64;
  const int l15 = lane & 15;
  const int khi = lane >> 4;
  const int swz = lane & 7;
  const int srow = lane >> 3;
  const int sslot = (lane & 7) ^ srow;

  f32x4 acc[4][4];
#pragma unroll
  for (int m = 0; m < 4; ++m)
#pragma unroll
    for (int n = 0; n < 4; ++n) acc[m][n] = (f32x4){0.f, 0.f, 0.f, 0.f};

  const int nK = Kd >> 6;
  for (int kt = 0; kt < nK; ++kt) {
    const int kb = kt << 6;
#pragma unroll
    for (int j = 0; j < 4; ++j) {
      const int c = wid * 4 + j;
      const long long rowg = 8 * c + srow;
      gload_lds16(Ab  + rowg * Kd + kb + sslot * 8, &Alds[c * 512]);
      gload_lds16(Btb + rowg * Kd + kb + sslot * 8, &Blds[c * 512]);
    }
    __syncthreads();
#pragma unroll
    for (int kk = 0; kk < 2; ++kk) {
      bf16x8 af[4], bfv[4];
#pragma unroll
      for (int m = 0; m < 4; ++m)
        af[m] = *(const bf16x8*)&Alds[(wr + m * 16 + l15) * 64 + (((kk * 4 + khi) ^ swz) << 3)];
#pragma unroll
      for (int n = 0; n < 4; ++n)
        bfv[n] = *(const bf16x8*)&Blds[(wc + n * 16 + l15) * 64 + (((kk * 4 + khi) ^ swz) << 3)];
#pragma unroll
      for (int m = 0; m < 4; ++m)
#pragma unroll
        for (int n = 0; n < 4; ++n)
          acc[m][n] = __builtin_amdgcn_mfma_f32_16x16x32_bf16(af[m], bfv[n], acc[m][n], 0, 0, 0);
    }
    __syncthreads();
  }

  const int crow = khi * 4;
#pragma unroll
  for (int m = 0; m < 4; ++m) {
#pragma unroll
    for (int n = 0; n < 4; ++n) {
      const long long col = (long long)nb * 128 + wc + n * 16 + l15;
      const float bvv = bias[nb * 128 + wc + n * 16 + l15];
#pragma unroll
      for (int j = 0; j < 4; ++j) {
        const long long row = (long long)mb * 128 + wr + m * 16 + crow + j;
        float v = acc[m][n][j] + bvv;
        if (GELU) v = 0.5f * v * (1.f + erff(v * 0.70710678118654752f));
        if (OUT_BF16)
          ((unsigned short*)Out)[row * N + col] = f2bf(v);
        else
          ((float*)Out)[row * N + col] = v;
      }
    }
  }
}

// ---------------- kernels ----------------

// fused: W1 transpose blocks (bid < nT) + router blocks (bid >= nT)
__global__ __launch_bounds__(256) void router_w1t_kernel(
    const float* __restrict__ x, const float* __restrict__ Wg,
    int* __restrict__ topi, float* __restrict__ topw,
    const float* __restrict__ W1, unsigned short* __restrict__ W1t, int nT) {
  __shared__ __align__(16) float tile[64][33];
  const int bid = blockIdx.x;
  if (bid < nT) {
    // W1: Kd=Dm, N=Hm; grid (Hm/32) x (Dm/64) x NE
    int nb = bid % (Hm / 32);
    int rest = bid / (Hm / 32);
    int kb = rest % (Dm / 64);
    int e = rest / (Dm / 64);
    transpose_body(tile, W1, W1t, Dm, Hm, e, nb * 32, kb * 64);
  } else {
    router_body(x, Wg, topi, topw, bid - nT);
  }
}

// plain transpose (fallback paths)
__global__ __launch_bounds__(256) void transpose_kernel(
    const float* __restrict__ W, unsigned short* __restrict__ Wt, int Kd, int N) {
  __shared__ __align__(16) float tile[64][33];
  transpose_body(tile, W, Wt, Kd, N, blockIdx.z, blockIdx.x * 32, blockIdx.y * 64);
}

// dispatch: parallel slot-major multi-counter prefix scan (1 block x 1024)
__global__ __launch_bounds__(1024) void dispatch_scan_kernel(
    const int* __restrict__ topi, int* __restrict__ pos, int* __restrict__ within) {
  __shared__ unsigned long long sc0[1024];
  __shared__ unsigned long long sc1[1024];
  const int tid = threadIdx.x;
  int myE[8];
  unsigned long long w0 = 0, w1 = 0;
#pragma unroll
  for (int j = 0; j < 8; ++j) {
    int a = tid * 8 + j;
    int k = a >> 12;
    int t = a & (T - 1);
    int e = topi[t * 2 + k];
    myE[j] = e;
    unsigned long long inc = 1ULL << (16 * (e & 3));
    if (e < 4) w0 += inc; else w1 += inc;
  }
  const unsigned long long l0 = w0, l1 = w1;
  sc0[tid] = w0; sc1[tid] = w1;
  __syncthreads();
  for (int off = 1; off < 1024; off <<= 1) {
    unsigned long long a0 = 0, a1 = 0;
    if (tid >= off) { a0 = sc0[tid - off]; a1 = sc1[tid - off]; }
    __syncthreads();
    w0 += a0; w1 += a1;
    sc0[tid] = w0; sc1[tid] = w1;
    __syncthreads();
  }
  unsigned long long e0 = w0 - l0, e1 = w1 - l1;
#pragma unroll
  for (int j = 0; j < 8; ++j) {
    int a = tid * 8 + j;
    int e = myE[j];
    int sh = 16 * (e & 3);
    int p;
    if (e < 4) { p = (int)((e0 >> sh) & 0xFFFF); e0 += 1ULL << sh; }
    else       { p = (int)((e1 >> sh) & 0xFFFF); e1 += 1ULL << sh; }
    pos[a] = p;
    within[a] = (p < CAP) ? 1 : 0;
  }
}

// scatter accepted tokens -> buf[e][p] (bf16)
__global__ __launch_bounds__(256) void scatter_kernel(
    const float* __restrict__ x, const int* __restrict__ topi,
    const int* __restrict__ pos, const int* __restrict__ within,
    unsigned short* __restrict__ buf) {
  int a = blockIdx.x;
  if (!within[a]) return;
  int k = a >> 12, t = a & (T - 1);
  int e = topi[t * 2 + k];
  int p = pos[a];
  const float* src = x + (size_t)t * Dm;
  unsigned short* dst = buf + ((size_t)e * CP + p) * Dm;
  int i = threadIdx.x * 4;
  float4 v = *(const float4*)(src + i);
  ushort4 o;
  o.x = f2bf(v.x); o.y = f2bf(v.y); o.z = f2bf(v.z); o.w = f2bf(v.w);
  *(ushort4*)(dst + i) = o;
}

// fused: GEMM1 blocks (bid < nGemm, e = bid%8 XCD-pinned) + W2 transpose blocks
__global__ __launch_bounds__(256) void gemm1_w2t_kernel(
    const unsigned short* __restrict__ buf, const unsigned short* __restrict__ W1t,
    const float* __restrict__ b1, unsigned short* __restrict__ h,
    const float* __restrict__ W2, unsigned short* __restrict__ W2t, int nGemm) {
  __shared__ __align__(16) char smem[32768];
  const int bid = blockIdx.x;
  if (bid < nGemm) {
    unsigned short* Alds = (unsigned short*)smem;
    unsigned short* Blds = (unsigned short*)(smem + 16384);
    const int e = bid & 7;          // nGemm = 2304 divisible by 8
    const int q = bid >> 3;
    const int mb = q % (CP / 128);  // m fastest: share B panel in L2
    const int nb = q / (CP / 128);
    gemm_body<true, true>(Alds, Blds,
        buf + (size_t)e * CP * Dm, W1t + (size_t)e * Hm * Dm, b1 + (size_t)e * Hm,
        (void*)(h + (size_t)e * CP * Hm), Dm, Hm, mb, nb);
  } else {
    float (*tile)[33] = (float(*)[33])smem;
    // W2: Kd=Hm, N=Dm; grid (Dm/32) x (Hm/64) x NE
    int tb = bid - nGemm;
    int nb = tb % (Dm / 32);
    int rest = tb / (Dm / 32);
    int kb = rest % (Hm / 64);
    int e = rest / (Hm / 64);
    transpose_body(tile, W2, W2t, Hm, Dm, e, nb * 32, kb * 64);
  }
}

// plain GEMM (GEMM2, and GEMM1 in fallback paths)
template <bool GELU, bool OUT_BF16>
__global__ __launch_bounds__(256) void gemm_bt_kernel(
    const unsigned short* __restrict__ Aall, const unsigned short* __restrict__ Btall,
    const float* __restrict__ biasAll, void* __restrict__ OutAll,
    int Kd, int N, long long sA, long long sB, long long sO, int sBias,
    int eb, int nM) {
  __shared__ __align__(16) char smem[32768];
  unsigned short* Alds = (unsigned short*)smem;
  unsigned short* Blds = (unsigned short*)(smem + 16384);
  const int lin = blockIdx.x;
  const int e = lin % eb;
  const int q = lin / eb;
  const int mb = q % nM;
  const int nb = q / nM;
  char* Out = (char*)OutAll + (long long)e * sO * (OUT_BF16 ? 2 : 4);
  gemm_body<GELU, OUT_BF16>(Alds, Blds,
      Aall + (long long)e * sA, Btall + (long long)e * sB,
      biasAll + (long long)e * sBias, (void*)Out, Kd, N, mb, nb);
}

// combine
__global__ __launch_bounds__(256) void combine_kernel(
    const float* __restrict__ y, const int* __restrict__ topi,
    const float* __restrict__ topw, const int* __restrict__ pos,
    const int* __restrict__ within, float* __restrict__ out) {
  int t = blockIdx.x;
  int i = threadIdx.x * 4;
  float4 r = {0.f, 0.f, 0.f, 0.f};
#pragma unroll
  for (int k = 0; k < 2; ++k) {
    int a = k * T + t;
    if (within[a]) {
      int e = topi[t * 2 + k];
      int p = pos[a];
      float w = topw[t * 2 + k];
      const float* yr = y + ((size_t)e * CP + p) * Dm;
      float4 v = *(const float4*)(yr + i);
      r.x += w * v.x; r.y += w * v.y; r.z += w * v.z; r.w += w * v.w;
    }
  }
  *(float4*)(out + (size_t)t * Dm + i) = r;
}

extern "C" void kernel_launch(void* const* d_in, const int* in_sizes, int n_in,
                              void* d_out, int out_size, void* d_ws, size_t ws_size,
                              hipStream_t stream) {
  const float* x  = (const float*)d_in[0];
  const float* Wg = (const float*)d_in[1];
  const float* W1 = (const float*)d_in[2];
  const float* b1 = (const float*)d_in[3];
  const float* W2 = (const float*)d_in[4];
  const float* b2 = (const float*)d_in[5];
  float* out = (float*)d_out;

  char* ws = (char*)d_ws;
  const size_t sz_h = (size_t)NE * CP * Hm * 2;        // 75.5 MB
  const size_t sz_y = (size_t)NE * CP * Dm * 4;        // 37.7 MB (buf bf16 aliases)
  const size_t sz_w = (size_t)NE * Hm * Dm * 2;        // 67.1 MB
  const size_t sz_small = (size_t)2 * T * 16;
  const size_t need_full = sz_h + sz_y + 2 * sz_w + sz_small;  // ~236 MiB
  const size_t need_mid  = sz_h + sz_y + sz_w + sz_small;      // ~172 MiB (proven fits)

  unsigned short* h = (unsigned short*)ws;
  char* yreg = ws + sz_h;
  unsigned short* buf = (unsigned short*)yreg;
  float* y = (float*)yreg;
  unsigned short* W1t = (unsigned short*)(ws + sz_h + sz_y);
  const bool full = (ws_size >= need_full);
  const bool mid  = (ws_size >= need_mid);
  unsigned short* W2t = full ? (W1t + sz_w / 2) : W1t;  // fallback: reuse W1t slot
  char* smallp = ws + sz_h + sz_y + (full ? 2 * sz_w : (mid ? sz_w : (size_t)2 * Hm * Dm * 2));
  int* topi   = (int*)smallp;
  float* topw = (float*)(topi + 2 * T);
  int* pos    = (int*)(topw + 2 * T);
  int* within = pos + 2 * T;

  const int nM = CP / 128;  // 9
  const int nT = (Hm / 32) * (Dm / 64) * NE;  // 16384 (same count for W2: (Dm/32)*(Hm/64)*NE)

  if (mid) {
    // router || W1-transpose
    router_w1t_kernel<<<nT + T / 4, 256, 0, stream>>>(x, Wg, topi, topw, W1, W1t, nT);
    dispatch_scan_kernel<<<1, 1024, 0, stream>>>(topi, pos, within);
    scatter_kernel<<<2 * T, 256, 0, stream>>>(x, topi, pos, within, buf);

    const int nGemm1 = NE * nM * (Hm / 128);  // 2304
    if (full) {
      // GEMM1 || W2-transpose
      gemm1_w2t_kernel<<<nGemm1 + nT, 256, 0, stream>>>(buf, W1t, b1, h, W2, W2t, nGemm1);
    } else {
      gemm_bt_kernel<true, true><<<nGemm1, 256, 0, stream>>>(
          buf, W1t, b1, (void*)h, Dm, Hm,
          (long long)CP * Dm, (long long)Hm * Dm, (long long)CP * Hm, Hm, NE, nM);
      transpose_kernel<<<dim3(Dm / 32, Hm / 64, NE), 256, 0, stream>>>(W2, W2t, Hm, Dm);
    }
    gemm_bt_kernel<false, false><<<NE * nM * (Dm / 128), 256, 0, stream>>>(
        h, W2t, b2, (void*)y, Hm, Dm,
        (long long)CP * Hm, (long long)Dm * Hm, (long long)CP * Dm, Dm, NE, nM);
  } else {
    // tight-memory path: batch weights 2 experts at a time (round-3 behavior)
    router_w1t_kernel<<<T / 4, 256, 0, stream>>>(x, Wg, topi, topw, W1, W1t, 0);
    dispatch_scan_kernel<<<1, 1024, 0, stream>>>(topi, pos, within);
    scatter_kernel<<<2 * T, 256, 0, stream>>>(x, topi, pos, within, buf);
    for (int e0 = 0; e0 < NE; e0 += 2) {
      transpose_kernel<<<dim3(Hm / 32, Dm / 64, 2), 256, 0, stream>>>(
          W1 + (size_t)e0 * Dm * Hm, W1t, Dm, Hm);
      gemm_bt_kernel<true, true><<<2 * nM * (Hm / 128), 256, 0, stream>>>(
          buf + (size_t)e0 * CP * Dm, W1t, b1 + (size_t)e0 * Hm,
          (void*)(h + (size_t)e0 * CP * Hm), Dm, Hm,
          (long long)CP * Dm, (long long)Hm * Dm, (long long)CP * Hm, Hm, 2, nM);
    }
    for (int e0 = 0; e0 < NE; e0 += 2) {
      transpose_kernel<<<dim3(Dm / 32, Hm / 64, 2), 256, 0, stream>>>(
          W2 + (size_t)e0 * Hm * Dm, W1t, Hm, Dm);
      gemm_bt_kernel<false, false><<<2 * nM * (Dm / 128), 256, 0, stream>>>(
          h + (size_t)e0 * CP * Hm, W1t, b2 + (size_t)e0 * Dm,
          (void*)(y + (size_t)e0 * CP * Dm), Hm, Dm,
          (long long)CP * Hm, (long long)Dm * Hm, (long long)CP * Dm, Dm, 2, nM);
    }
  }

  combine_kernel<<<T, 256, 0, stream>>>(y, topi, topw, pos, within, out);
}

// Round 5
// 346.998 us; speedup vs baseline: 1.0598x; 1.0598x over previous
//
#include <hip/hip_runtime.h>

typedef __attribute__((ext_vector_type(8))) __bf16 bf16x8;
typedef __attribute__((ext_vector_type(4))) float f32x4;

constexpr int T  = 4096;   // tokens
constexpr int Dm = 1024;   // model dim
constexpr int Hm = 4096;   // hidden dim
constexpr int NE = 8;      // experts
constexpr int CAP = 1075;  // capacity  round(2*4096*1.05/8)
constexpr int CP  = 1152;  // capacity padded to 9*128

static __device__ __forceinline__ unsigned short f2bf(float f) {
  unsigned int u = __float_as_uint(f);
  u += 0x7FFFu + ((u >> 16) & 1u);   // RNE
  return (unsigned short)(u >> 16);
}

static __device__ __forceinline__ void gload_lds16(const void* g, void* l) {
  __builtin_amdgcn_global_load_lds(
      (const __attribute__((address_space(1))) void*)g,
      (__attribute__((address_space(3))) void*)l, 16, 0, 0);
}

// ---------------- device bodies ----------------

// transpose+convert one 64(k) x 32(n) tile: W [Kd][N] f32 -> Wt [N][Kd] bf16
static __device__ __forceinline__ void transpose_body(
    float (*tile)[33], const float* __restrict__ W, unsigned short* __restrict__ Wt,
    int Kd, int N, int e, int n0, int k0) {
  const float* src = W + ((long long)e * Kd + k0) * N + n0;
  const int tid = threadIdx.x;
  const int r = tid >> 3;            // 0..31
  const int c4 = (tid & 7) * 4;
#pragma unroll
  for (int hh = 0; hh < 2; ++hh) {
    float4 v = *(const float4*)(src + (long long)(r + 32 * hh) * N + c4);
    tile[r + 32 * hh][c4] = v.x; tile[r + 32 * hh][c4 + 1] = v.y;
    tile[r + 32 * hh][c4 + 2] = v.z; tile[r + 32 * hh][c4 + 3] = v.w;
  }
  __syncthreads();
  const int n = tid >> 4;            // 0..15
  const int k4 = (tid & 15) * 4;
  unsigned short* dst = Wt + ((long long)e * N + n0) * Kd + k0;
#pragma unroll
  for (int hh = 0; hh < 2; ++hh) {
    int nn = n + 16 * hh;
    ushort4 o;
    o.x = f2bf(tile[k4][nn]);     o.y = f2bf(tile[k4 + 1][nn]);
    o.z = f2bf(tile[k4 + 2][nn]); o.w = f2bf(tile[k4 + 3][nn]);
    *(ushort4*)(dst + (long long)nn * Kd + k4) = o;
  }
}

// router body for token group (4 tokens per block of 256 threads)
static __device__ __forceinline__ void router_body(
    const float* __restrict__ x, const float* __restrict__ Wg,
    int* __restrict__ topi, float* __restrict__ topw, int blk) {
  int t = blk * 4 + (threadIdx.x >> 6);
  int lane = threadIdx.x & 63;
  const float* xr = x + (size_t)t * Dm;
  float acc[NE];
#pragma unroll
  for (int e = 0; e < NE; ++e) acc[e] = 0.f;
  for (int i = lane * 4; i < Dm; i += 256) {
    float4 xv = *(const float4*)(xr + i);
#pragma unroll
    for (int e = 0; e < NE; ++e) {
      float4 wv = *(const float4*)(Wg + e * Dm + i);
      acc[e] += xv.x * wv.x + xv.y * wv.y + xv.z * wv.z + xv.w * wv.w;
    }
  }
#pragma unroll
  for (int off = 32; off > 0; off >>= 1) {
#pragma unroll
    for (int e = 0; e < NE; ++e) acc[e] += __shfl_xor(acc[e], off, 64);
  }
  if (lane == 0) {
    float mx = acc[0];
#pragma unroll
    for (int e = 1; e < NE; ++e) mx = fmaxf(mx, acc[e]);
    float g[NE];
    float s = 0.f;
#pragma unroll
    for (int e = 0; e < NE; ++e) { g[e] = expf(acc[e] - mx); s += g[e]; }
    int i0 = 0; float v0 = g[0];
#pragma unroll
    for (int e = 1; e < NE; ++e) if (g[e] > v0) { v0 = g[e]; i0 = e; }
    int i1 = -1; float v1 = -1e30f;
#pragma unroll
    for (int e = 0; e < NE; ++e) {
      if (e == i0) continue;
      if (g[e] > v1) { v1 = g[e]; i1 = e; }
    }
    float inv = 1.f / s;
    topi[t * 2] = i0; topi[t * 2 + 1] = i1;
    topw[t * 2] = v0 * inv; topw[t * 2 + 1] = v1 * inv;
  }
}

// GEMM tile body: C[mb*128..][nb*128..] = A @ Bt^T + bias, m97-swizzled staging.
template <bool GELU, bool OUT_BF16>
static __device__ __forceinline__ void gemm_body(
    unsigned short* Alds, unsigned short* Blds,
    const unsigned short* __restrict__ A, const unsigned short* __restrict__ Bt,
    const float* __restrict__ bias, void* __restrict__ Out,
    int Kd, int N, int mb, int nb) {
  const unsigned short* Ab  = A  + (long long)mb * 128 * Kd;
  const unsigned short* Btb = Bt + (long long)nb * 128 * Kd;

  const int tid = threadIdx.x;
  const int lane = tid & 63;
  const int wid = tid >> 6;
  const int wr = (wid >> 1) * 64;
  const int wc = (wid & 1) * 64;
  const int l15 = lane & 15;
  const int khi = lane >> 4;
  const int swz = lane & 7;
  const int srow = lane >> 3;
  const int sslot = (lane & 7) ^ srow;

  f32x4 acc[4][4];
#pragma unroll
  for (int m = 0; m < 4; ++m)
#pragma unroll
    for (int n = 0; n < 4; ++n) acc[m][n] = (f32x4){0.f, 0.f, 0.f, 0.f};

  const int nK = Kd >> 6;
  for (int kt = 0; kt < nK; ++kt) {
    const int kb = kt << 6;
#pragma unroll
    for (int j = 0; j < 4; ++j) {
      const int c = wid * 4 + j;
      const long long rowg = 8 * c + srow;
      gload_lds16(Ab  + rowg * Kd + kb + sslot * 8, &Alds[c * 512]);
      gload_lds16(Btb + rowg * Kd + kb + sslot * 8, &Blds[c * 512]);
    }
    __syncthreads();
#pragma unroll
    for (int kk = 0; kk < 2; ++kk) {
      bf16x8 af[4], bfv[4];
#pragma unroll
      for (int m = 0; m < 4; ++m)
        af[m] = *(const bf16x8*)&Alds[(wr + m * 16 + l15) * 64 + (((kk * 4 + khi) ^ swz) << 3)];
#pragma unroll
      for (int n = 0; n < 4; ++n)
        bfv[n] = *(const bf16x8*)&Blds[(wc + n * 16 + l15) * 64 + (((kk * 4 + khi) ^ swz) << 3)];
#pragma unroll
      for (int m = 0; m < 4; ++m)
#pragma unroll
        for (int n = 0; n < 4; ++n)
          acc[m][n] = __builtin_amdgcn_mfma_f32_16x16x32_bf16(af[m], bfv[n], acc[m][n], 0, 0, 0);
    }
    __syncthreads();
  }

  const int crow = khi * 4;
#pragma unroll
  for (int m = 0; m < 4; ++m) {
#pragma unroll
    for (int n = 0; n < 4; ++n) {
      const long long col = (long long)nb * 128 + wc + n * 16 + l15;
      const float bvv = bias[nb * 128 + wc + n * 16 + l15];
#pragma unroll
      for (int j = 0; j < 4; ++j) {
        const long long row = (long long)mb * 128 + wr + m * 16 + crow + j;
        float v = acc[m][n][j] + bvv;
        if (GELU) v = 0.5f * v * (1.f + erff(v * 0.70710678118654752f));
        if (OUT_BF16)
          ((unsigned short*)Out)[row * N + col] = f2bf(v);
        else
          ((float*)Out)[row * N + col] = v;
      }
    }
  }
}

// ---------------- kernels ----------------

// fused pre-pass: router blocks (bid < nR), W1-transpose, then W2-transpose.
// All pure memory/VALU blocks (no MFMA dilution). nT blocks per weight matrix.
__global__ __launch_bounds__(256) void fused_pre_kernel(
    const float* __restrict__ x, const float* __restrict__ Wg,
    int* __restrict__ topi, float* __restrict__ topw,
    const float* __restrict__ W1, unsigned short* __restrict__ W1t,
    const float* __restrict__ W2, unsigned short* __restrict__ W2t,
    int nR, int nT) {
  __shared__ __align__(16) float tile[64][33];
  const int bid = blockIdx.x;
  if (bid < nR) {
    router_body(x, Wg, topi, topw, bid);
  } else if (bid < nR + nT) {
    // W1: Kd=Dm, N=Hm; layout (Hm/32) x (Dm/64) x NE
    int tb = bid - nR;
    int nb = tb % (Hm / 32);
    int rest = tb / (Hm / 32);
    int kb = rest % (Dm / 64);
    int e = rest / (Dm / 64);
    transpose_body(tile, W1, W1t, Dm, Hm, e, nb * 32, kb * 64);
  } else {
    // W2: Kd=Hm, N=Dm; layout (Dm/32) x (Hm/64) x NE
    int tb = bid - nR - nT;
    int nb = tb % (Dm / 32);
    int rest = tb / (Dm / 32);
    int kb = rest % (Hm / 64);
    int e = rest / (Hm / 64);
    transpose_body(tile, W2, W2t, Hm, Dm, e, nb * 32, kb * 64);
  }
}

// plain transpose (fallback paths)
__global__ __launch_bounds__(256) void transpose_kernel(
    const float* __restrict__ W, unsigned short* __restrict__ Wt, int Kd, int N) {
  __shared__ __align__(16) float tile[64][33];
  transpose_body(tile, W, Wt, Kd, N, blockIdx.z, blockIdx.x * 32, blockIdx.y * 64);
}

// dispatch: parallel slot-major multi-counter prefix scan (1 block x 1024)
__global__ __launch_bounds__(1024) void dispatch_scan_kernel(
    const int* __restrict__ topi, int* __restrict__ pos, int* __restrict__ within) {
  __shared__ unsigned long long sc0[1024];
  __shared__ unsigned long long sc1[1024];
  const int tid = threadIdx.x;
  int myE[8];
  unsigned long long w0 = 0, w1 = 0;
#pragma unroll
  for (int j = 0; j < 8; ++j) {
    int a = tid * 8 + j;
    int k = a >> 12;
    int t = a & (T - 1);
    int e = topi[t * 2 + k];
    myE[j] = e;
    unsigned long long inc = 1ULL << (16 * (e & 3));
    if (e < 4) w0 += inc; else w1 += inc;
  }
  const unsigned long long l0 = w0, l1 = w1;
  sc0[tid] = w0; sc1[tid] = w1;
  __syncthreads();
  for (int off = 1; off < 1024; off <<= 1) {
    unsigned long long a0 = 0, a1 = 0;
    if (tid >= off) { a0 = sc0[tid - off]; a1 = sc1[tid - off]; }
    __syncthreads();
    w0 += a0; w1 += a1;
    sc0[tid] = w0; sc1[tid] = w1;
    __syncthreads();
  }
  unsigned long long e0 = w0 - l0, e1 = w1 - l1;
#pragma unroll
  for (int j = 0; j < 8; ++j) {
    int a = tid * 8 + j;
    int e = myE[j];
    int sh = 16 * (e & 3);
    int p;
    if (e < 4) { p = (int)((e0 >> sh) & 0xFFFF); e0 += 1ULL << sh; }
    else       { p = (int)((e1 >> sh) & 0xFFFF); e1 += 1ULL << sh; }
    pos[a] = p;
    within[a] = (p < CAP) ? 1 : 0;
  }
}

// scatter accepted tokens -> buf[e][p] (bf16)
__global__ __launch_bounds__(256) void scatter_kernel(
    const float* __restrict__ x, const int* __restrict__ topi,
    const int* __restrict__ pos, const int* __restrict__ within,
    unsigned short* __restrict__ buf) {
  int a = blockIdx.x;
  if (!within[a]) return;
  int k = a >> 12, t = a & (T - 1);
  int e = topi[t * 2 + k];
  int p = pos[a];
  const float* src = x + (size_t)t * Dm;
  unsigned short* dst = buf + ((size_t)e * CP + p) * Dm;
  int i = threadIdx.x * 4;
  float4 v = *(const float4*)(src + i);
  ushort4 o;
  o.x = f2bf(v.x); o.y = f2bf(v.y); o.z = f2bf(v.z); o.w = f2bf(v.w);
  *(ushort4*)(dst + i) = o;
}

// plain GEMM, 1-D grid, e = lin % eb (XCD pin), m fastest within expert
template <bool GELU, bool OUT_BF16>
__global__ __launch_bounds__(256) void gemm_bt_kernel(
    const unsigned short* __restrict__ Aall, const unsigned short* __restrict__ Btall,
    const float* __restrict__ biasAll, void* __restrict__ OutAll,
    int Kd, int N, long long sA, long long sB, long long sO, int sBias,
    int eb, int nM) {
  __shared__ __align__(16) char smem[32768];
  unsigned short* Alds = (unsigned short*)smem;
  unsigned short* Blds = (unsigned short*)(smem + 16384);
  const int lin = blockIdx.x;
  const int e = lin % eb;
  const int q = lin / eb;
  const int mb = q % nM;
  const int nb = q / nM;
  char* Out = (char*)OutAll + (long long)e * sO * (OUT_BF16 ? 2 : 4);
  gemm_body<GELU, OUT_BF16>(Alds, Blds,
      Aall + (long long)e * sA, Btall + (long long)e * sB,
      biasAll + (long long)e * sBias, (void*)Out, Kd, N, mb, nb);
}

// combine
__global__ __launch_bounds__(256) void combine_kernel(
    const float* __restrict__ y, const int* __restrict__ topi,
    const float* __restrict__ topw, const int* __restrict__ pos,
    const int* __restrict__ within, float* __restrict__ out) {
  int t = blockIdx.x;
  int i = threadIdx.x * 4;
  float4 r = {0.f, 0.f, 0.f, 0.f};
#pragma unroll
  for (int k = 0; k < 2; ++k) {
    int a = k * T + t;
    if (within[a]) {
      int e = topi[t * 2 + k];
      int p = pos[a];
      float w = topw[t * 2 + k];
      const float* yr = y + ((size_t)e * CP + p) * Dm;
      float4 v = *(const float4*)(yr + i);
      r.x += w * v.x; r.y += w * v.y; r.z += w * v.z; r.w += w * v.w;
    }
  }
  *(float4*)(out + (size_t)t * Dm + i) = r;
}

extern "C" void kernel_launch(void* const* d_in, const int* in_sizes, int n_in,
                              void* d_out, int out_size, void* d_ws, size_t ws_size,
                              hipStream_t stream) {
  const float* x  = (const float*)d_in[0];
  const float* Wg = (const float*)d_in[1];
  const float* W1 = (const float*)d_in[2];
  const float* b1 = (const float*)d_in[3];
  const float* W2 = (const float*)d_in[4];
  const float* b2 = (const float*)d_in[5];
  float* out = (float*)d_out;

  char* ws = (char*)d_ws;
  const size_t sz_h = (size_t)NE * CP * Hm * 2;        // 75.5 MB
  const size_t sz_y = (size_t)NE * CP * Dm * 4;        // 37.7 MB (buf bf16 aliases)
  const size_t sz_w = (size_t)NE * Hm * Dm * 2;        // 67.1 MB
  const size_t sz_small = (size_t)2 * T * 16;
  const size_t need_full = sz_h + sz_y + 2 * sz_w + sz_small;  // ~236 MiB
  const size_t need_mid  = sz_h + sz_y + sz_w + sz_small;      // ~172 MiB (proven fits)

  unsigned short* h = (unsigned short*)ws;
  char* yreg = ws + sz_h;
  unsigned short* buf = (unsigned short*)yreg;
  float* y = (float*)yreg;
  unsigned short* W1t = (unsigned short*)(ws + sz_h + sz_y);
  const bool full = (ws_size >= need_full);
  const bool mid  = (ws_size >= need_mid);
  unsigned short* W2t = full ? (W1t + sz_w / 2) : W1t;  // fallback: reuse W1t slot
  char* smallp = ws + sz_h + sz_y + (full ? 2 * sz_w : (mid ? sz_w : (size_t)2 * Hm * Dm * 2));
  int* topi   = (int*)smallp;
  float* topw = (float*)(topi + 2 * T);
  int* pos    = (int*)(topw + 2 * T);
  int* within = pos + 2 * T;

  const int nM = CP / 128;  // 9
  const int nR = T / 4;     // 1024 router blocks
  const int nT = (Hm / 32) * (Dm / 64) * NE;  // 16384 tiles per weight matrix
  const int nGemm1 = NE * nM * (Hm / 128);    // 2304
  const int nGemm2 = NE * nM * (Dm / 128);    // 576

  if (full) {
    // one fused pre-pass: router + W1t + W2t (all BW-bound, overlap freely)
    fused_pre_kernel<<<nR + 2 * nT, 256, 0, stream>>>(
        x, Wg, topi, topw, W1, W1t, W2, W2t, nR, nT);
    dispatch_scan_kernel<<<1, 1024, 0, stream>>>(topi, pos, within);
    scatter_kernel<<<2 * T, 256, 0, stream>>>(x, topi, pos, within, buf);
    gemm_bt_kernel<true, true><<<nGemm1, 256, 0, stream>>>(
        buf, W1t, b1, (void*)h, Dm, Hm,
        (long long)CP * Dm, (long long)Hm * Dm, (long long)CP * Hm, Hm, NE, nM);
    gemm_bt_kernel<false, false><<<nGemm2, 256, 0, stream>>>(
        h, W2t, b2, (void*)y, Hm, Dm,
        (long long)CP * Hm, (long long)Dm * Hm, (long long)CP * Dm, Dm, NE, nM);
  } else if (mid) {
    // router + W1t fused; W2t after GEMM1 (reuses W1t slot) — round-3 behavior
    fused_pre_kernel<<<nR + nT, 256, 0, stream>>>(
        x, Wg, topi, topw, W1, W1t, W2, W2t, nR, nT);
    dispatch_scan_kernel<<<1, 1024, 0, stream>>>(topi, pos, within);
    scatter_kernel<<<2 * T, 256, 0, stream>>>(x, topi, pos, within, buf);
    gemm_bt_kernel<true, true><<<nGemm1, 256, 0, stream>>>(
        buf, W1t, b1, (void*)h, Dm, Hm,
        (long long)CP * Dm, (long long)Hm * Dm, (long long)CP * Hm, Hm, NE, nM);
    transpose_kernel<<<dim3(Dm / 32, Hm / 64, NE), 256, 0, stream>>>(W2, W2t, Hm, Dm);
    gemm_bt_kernel<false, false><<<nGemm2, 256, 0, stream>>>(
        h, W2t, b2, (void*)y, Hm, Dm,
        (long long)CP * Hm, (long long)Dm * Hm, (long long)CP * Dm, Dm, NE, nM);
  } else {
    // tight-memory path: batch weights 2 experts at a time
    fused_pre_kernel<<<nR, 256, 0, stream>>>(
        x, Wg, topi, topw, W1, W1t, W2, W2t, nR, 0);
    dispatch_scan_kernel<<<1, 1024, 0, stream>>>(topi, pos, within);
    scatter_kernel<<<2 * T, 256, 0, stream>>>(x, topi, pos, within, buf);
    for (int e0 = 0; e0 < NE; e0 += 2) {
      transpose_kernel<<<dim3(Hm / 32, Dm / 64, 2), 256, 0, stream>>>(
          W1 + (size_t)e0 * Dm * Hm, W1t, Dm, Hm);
      gemm_bt_kernel<true, true><<<2 * nM * (Hm / 128), 256, 0, stream>>>(
          buf + (size_t)e0 * CP * Dm, W1t, b1 + (size_t)e0 * Hm,
          (void*)(h + (size_t)e0 * CP * Hm), Dm, Hm,
          (long long)CP * Dm, (long long)Hm * Dm, (long long)CP * Hm, Hm, 2, nM);
    }
    for (int e0 = 0; e0 < NE; e0 += 2) {
      transpose_kernel<<<dim3(Dm / 32, Hm / 64, 2), 256, 0, stream>>>(
          W2 + (size_t)e0 * Hm * Dm, W1t, Hm, Dm);
      gemm_bt_kernel<false, false><<<2 * nM * (Dm / 128), 256, 0, stream>>>(
          h + (size_t)e0 * CP * Hm, W1t, b2 + (size_t)e0 * Dm,
          (void*)(y + (size_t)e0 * CP * Dm), Hm, Dm,
          (long long)CP * Hm, (long long)Dm * Hm, (long long)CP * Dm, Dm, 2, nM);
    }
  }

  combine_kernel<<<T, 256, 0, stream>>>(y, topi, topw, pos, within, out);
}